// Round 5
// baseline (636.039 us; speedup 1.0000x reference)
//
#include <hip/hip_runtime.h>

// Fused tanh-RNN: y[b,t] = W_fc . h[b,t] + b_fc,  h_t = tanh(x_t W_ih^T + b_ih + b_hh + h_{t-1} W_hh^T)
// B=2048, S=512, I=40, H=64.
//
// One 64-lane wave per block, one block per batch element (2048 blocks ->
// 8 waves/CU = 2/SIMD, perfectly balanced). Lane j owns hidden unit j.
//  - W_ih row j (40 f32), W_hh row j (64 f32) in VGPRs as f32x2 pairs ->
//    v_pk_fma_f32 (halves VALU issue slots; 2x FLOPs if dual-rate).
//  - h exchanged via wave-private LDS ping-pong: lane j writes h[j], all
//    lanes broadcast-read (uniform-address b128, conflict-free). Single-wave
//    DS ordering => zero barriers in the whole kernel.
//  - x is NOT staged in LDS (DS-pipe audit: 10 b128 broadcasts/step made the
//    shared DS pipe the likely bottleneck at 8 waves/CU). The xw pre-pass
//    reads x straight from global with wave-uniform addresses -> one L1-line
//    broadcast per load on the otherwise-idle VMEM pipe. The next block's
//    5 KiB of x is warmed into L1/L2 by coalesced touch loads issued before
//    the serial phase and asm-consumed at loop-body end (DCE-proof, and the
//    vmcnt wait lands ~5000 cy after issue => ~free).
//  - xw pre-pass: input projection for the 32 staged steps into 32 VGPRs
//    with full ILP (off the serial chain).
//  - Batched head: per step, gs[s][lane] = h*wfc (1 mul + 1 ds_write, no
//    per-step shuffle chain). At block end: lane l sums half of row (l&31),
//    one shfl_xor(32) combine, 128 B coalesced store.
// All loops fully unrolled -> compile-time indices only (no scratch).
// DS budget/step/wave: 4 b128 broadcast reads + 2 b32 writes + ~0.3 head.

#define RNN_B 2048
#define RNN_S 512
#define RNN_I 40
#define RNN_H 64
#define TBLK  32                  // timesteps per compute block
#define GPAD  72                  // gs row stride in floats (16B-aligned rows)

typedef float f32x2 __attribute__((ext_vector_type(2)));

__device__ __forceinline__ f32x2 mk2(float a, float b) {
    f32x2 v; v.x = a; v.y = b; return v;
}

__device__ __forceinline__ f32x2 fma2(f32x2 a, f32x2 b, f32x2 c) {
#if __has_builtin(__builtin_elementwise_fma)
    return __builtin_elementwise_fma(a, b, c);   // -> v_pk_fma_f32
#else
    return mk2(fmaf(a.x, b.x, c.x), fmaf(a.y, b.y, c.y));
#endif
}

__device__ __forceinline__ float fast_tanh(float p) {
    // tanh(p) = 1 - 2/(e^{2p}+1). Saturation-safe: exp->inf => 1, exp->0 => -1.
#if __has_builtin(__builtin_amdgcn_exp2f)
    const float e = __builtin_amdgcn_exp2f(p * 2.885390081777927f); // 2*log2(e)
#else
    const float e = __expf(2.f * p);
#endif
    return 1.f - __fdividef(2.f, e + 1.f);
}

__global__ __launch_bounds__(64, 2)
void rnn_fused(const float* __restrict__ x,
               const float* __restrict__ W_ih,
               const float* __restrict__ W_hh,
               const float* __restrict__ b_ih,
               const float* __restrict__ b_hh,
               const float* __restrict__ W_fc,
               const float* __restrict__ b_fc,
               float* __restrict__ out)
{
    const int lane = threadIdx.x & 63;
    const int b    = blockIdx.x;

    __shared__ float hs[2][RNN_H];      // ping-pong hidden state
    __shared__ float gs[TBLK][GPAD];    // per-step h*wfc, for batched head

    // Per-lane weight rows -> f32x2 register pairs (one-time, cached loads).
    f32x2 wih2[RNN_I / 2];
#pragma unroll
    for (int k = 0; k < RNN_I / 2; ++k)
        wih2[k] = *(const f32x2*)&W_ih[lane * RNN_I + 2 * k];
    f32x2 whh2[RNN_H / 2];
#pragma unroll
    for (int k = 0; k < RNN_H / 2; ++k)
        whh2[k] = *(const f32x2*)&W_hh[lane * RNN_H + 2 * k];
    const float bias = b_ih[lane] + b_hh[lane];
    const float wfc  = W_fc[lane];
    const float bfc  = b_fc[0];

    hs[0][lane] = 0.f;   // h0 = 0

    const float* __restrict__ xrow = x + (size_t)b * (RNN_S * RNN_I);
    float* __restrict__ orow       = out + (size_t)b * RNN_S;

    // Warm block 0's x into L1/L2 (coalesced, 16 B/lane). Consumed below.
    float4 tch[5];
#pragma unroll
    for (int i = 0; i < 5; ++i)
        tch[i] = *(const float4*)&xrow[256 * i + 4 * lane];

    for (int T = 0; T < RNN_S; T += TBLK) {
        const bool more = (T + TBLK) < RNN_S;

        // ---- xw pre-pass: input projection for 32 steps, full ILP.
        // Wave-uniform global reads -> L1 broadcast (VMEM pipe, no DS).
        float xw[TBLK];
#pragma unroll
        for (int s = 0; s < TBLK; ++s) {
            const float4* __restrict__ xsrc =
                (const float4*)(xrow + (size_t)(T + s) * RNN_I);
            f32x2 a0 = mk2(bias, 0.f);
            f32x2 a1 = mk2(0.f, 0.f);
#pragma unroll
            for (int k4 = 0; k4 < RNN_I / 4; ++k4) {
                const float4 xv = xsrc[k4];
                a0 = fma2(mk2(xv.x, xv.y), wih2[2 * k4 + 0], a0);
                a1 = fma2(mk2(xv.z, xv.w), wih2[2 * k4 + 1], a1);
            }
            xw[s] = (a0.x + a0.y) + (a1.x + a1.y);
        }

        // ---- issue next block's warm-touch loads (land during serial phase).
        float4 tn[5];
        if (more) {
#pragma unroll
            for (int i = 0; i < 5; ++i)
                tn[i] = *(const float4*)&xrow[(T + TBLK) * RNN_I + 256 * i + 4 * lane];
        }

        // ---- serial recurrent phase: 32 steps, fully unrolled, no shuffles.
#pragma unroll
        for (int s = 0; s < TBLK; ++s) {
            const int hc = s & 1;

            f32x2 a0 = mk2(xw[s], 0.f);
            f32x2 a1 = mk2(0.f, 0.f);
            f32x2 a2 = mk2(0.f, 0.f);
            f32x2 a3 = mk2(0.f, 0.f);
#pragma unroll
            for (int q = 0; q < RNN_H / 16; ++q) {
                const float4 h0 = *(const float4*)&hs[hc][16 * q];
                const float4 h1 = *(const float4*)&hs[hc][16 * q + 4];
                const float4 h2 = *(const float4*)&hs[hc][16 * q + 8];
                const float4 h3 = *(const float4*)&hs[hc][16 * q + 12];
                a0 = fma2(mk2(h0.x, h0.y), whh2[8 * q + 0], a0);
                a1 = fma2(mk2(h0.z, h0.w), whh2[8 * q + 1], a1);
                a2 = fma2(mk2(h1.x, h1.y), whh2[8 * q + 2], a2);
                a3 = fma2(mk2(h1.z, h1.w), whh2[8 * q + 3], a3);
                a0 = fma2(mk2(h2.x, h2.y), whh2[8 * q + 4], a0);
                a1 = fma2(mk2(h2.z, h2.w), whh2[8 * q + 5], a1);
                a2 = fma2(mk2(h3.x, h3.y), whh2[8 * q + 6], a2);
                a3 = fma2(mk2(h3.z, h3.w), whh2[8 * q + 7], a3);
            }
            const float pre = ((a0.x + a0.y) + (a1.x + a1.y))
                            + ((a2.x + a2.y) + (a3.x + a3.y));

            const float h = fast_tanh(pre);
            hs[hc ^ 1][lane] = h;       // next step's input
            gs[s][lane]      = h * wfc; // head contribution, reduced below
        }

        // ---- batched head: out[T+r] = sum_k gs[r][k] + bfc.
        {
            const int r    = lane & 31;
            const int half = lane >> 5;
            f32x2 pa = mk2(0.f, 0.f);
            f32x2 pb = mk2(0.f, 0.f);
#pragma unroll
            for (int c = 0; c < 8; ++c) {
                const float4 v = *(const float4*)&gs[r][32 * half + 4 * c];
                pa = mk2(pa.x + v.x, pa.y + v.y);
                pb = mk2(pb.x + v.z, pb.y + v.w);
            }
            float p = (pa.x + pa.y) + (pb.x + pb.y);
            p += __shfl_xor(p, 32, 64);
            if (half == 0) orow[T + r] = p + bfc;   // 128 B coalesced store
        }

        // ---- consume touch loads (keeps them alive; wait is ~free here:
        // they were issued ~5000 cy ago). Next pre-pass then hits L1/L2.
#pragma unroll
        for (int i = 0; i < 5; ++i)
            asm volatile("" :: "v"(tch[i].x), "v"(tch[i].y),
                              "v"(tch[i].z), "v"(tch[i].w));
        if (more) {
#pragma unroll
            for (int i = 0; i < 5; ++i) tch[i] = tn[i];
        }
    }
}

extern "C" void kernel_launch(void* const* d_in, const int* in_sizes, int n_in,
                              void* d_out, int out_size, void* d_ws, size_t ws_size,
                              hipStream_t stream) {
    const float* x    = (const float*)d_in[0];
    const float* W_ih = (const float*)d_in[1];
    const float* W_hh = (const float*)d_in[2];
    const float* b_ih = (const float*)d_in[3];
    const float* b_hh = (const float*)d_in[4];
    const float* W_fc = (const float*)d_in[5];
    const float* b_fc = (const float*)d_in[6];
    float* out = (float*)d_out;

    dim3 grid(RNN_B);
    dim3 block(64);
    hipLaunchKernelGGL(rnn_fused, grid, block, 0, stream,
                       x, W_ih, W_hh, b_ih, b_hh, W_fc, b_fc, out);
}